// Round 9
// baseline (58.675 us; speedup 1.0000x reference)
//
#include <hip/hip_runtime.h>

#define N_AB  1024
#define NHALF 1025
#define NFULL 2049
#define HDIM  64
#define PLANE ((size_t)N_AB * NFULL)
#define C2L   2.8853900817779268f   // 2*log2(e)
#define TLN2  1.3862943611198906f   // 2*ln(2);  C2L * TLN2 = 4

typedef __bf16 bf16x8 __attribute__((ext_vector_type(8)));
typedef __bf16 bf16x4 __attribute__((ext_vector_type(4)));
typedef float  f32x4  __attribute__((ext_vector_type(4)));
typedef float  f32x2  __attribute__((ext_vector_type(2)));

#define MFMA16(A,B,C) __builtin_amdgcn_mfma_f32_16x16x32_bf16(A,B,C,0,0,0)

// Packed (float2) tanh core: S2 = z*2log2e (pair). H2 = tanh(z), T2 = u-u^2 (1-H^2 = 4T).
#define ACT2(S2,H2,T2) { \
    f32x2 _e; _e.x = __builtin_amdgcn_exp2f(S2.x); _e.y = __builtin_amdgcn_exp2f(S2.y); \
    f32x2 _d = _e + 1.0f; \
    f32x2 _u; _u.x = __builtin_amdgcn_rcpf(_d.x); _u.y = __builtin_amdgcn_rcpf(_d.y); \
    H2 = __builtin_elementwise_fma(_km2, _u, _k1); \
    T2 = __builtin_elementwise_fma(-_u, _u, _u); }

// layer-1 element pair: WC2 = w0*C2L, BC2 = b0*C2L ; h -> BV, (t*WC2)*TLN2 = 4t*w0 -> BT
#define L1P(I0, WC2, BC2, BV, BT) { \
    f32x2 _s = __builtin_elementwise_fma(WC2, x2, BC2); \
    f32x2 _h, _t; ACT2(_s,_h,_t) \
    f32x2 _bt = (_t * WC2) * TLN2; \
    BV[I0] = (__bf16)_h.x; BV[I0+1] = (__bf16)_h.y; \
    BT[I0] = (__bf16)_bt.x; BT[I0+1] = (__bf16)_bt.y; }

// one L1 half (8 hidden units): JIT-load 4 quads (w0q0 w0q1 b0q0 b0q1) from LDS table
#define L1STEP(C1, S, BV, BT) { \
    f32x4 _w0q0 = (C1)[(S)*16+0], _w0q1 = (C1)[(S)*16+1]; \
    f32x4 _b0q0 = (C1)[(S)*16+2], _b0q1 = (C1)[(S)*16+3]; \
    L1P(0, _w0q0.xy, _b0q0.xy, BV, BT) \
    L1P(2, _w0q0.zw, _b0q0.zw, BV, BT) \
    L1P(4, _w0q1.xy, _b0q1.xy, BV, BT) \
    L1P(6, _w0q1.zw, _b0q1.zw, BV, BT) }

// layer-2 element pair: AV2=z2pre, AT2=dz2pre, B1C2=b1*C2L ; accumulate L3 partial pairs.
// _dh carries t*dacc only; missing *4 folded into the 8.0f in da/db.
#define L2P(AV2, AT2, B1C2, W20_2, W21_2) { \
    f32x2 _s = __builtin_elementwise_fma(AV2, c2l2, B1C2); \
    f32x2 _h, _t; ACT2(_s,_h,_t) \
    f32x2 _dh = _t * (AT2); \
    pv0_2 = __builtin_elementwise_fma(W20_2, _h,  pv0_2); \
    pv1_2 = __builtin_elementwise_fma(W21_2, _h,  pv1_2); \
    pt0_2 = __builtin_elementwise_fma(W20_2, _dh, pt0_2); \
    pt1_2 = __builtin_elementwise_fma(W21_2, _dh, pt1_2); }

// one L2 quarter (4 hidden units): JIT-load 3 quads (b1c | w2a | w2b) from LDS table
#define L2STEP(C2, Q, AV, AT) { \
    f32x4 _b1q  = (C2)[(Q)*12+0]; \
    f32x4 _w2aq = (C2)[(Q)*12+1]; \
    f32x4 _w2bq = (C2)[(Q)*12+2]; \
    L2P(AV.xy, AT.xy, _b1q.xy, _w2aq.xy, _w2bq.xy) \
    L2P(AV.zw, AT.zw, _b1q.zw, _w2aq.zw, _w2bq.zw) }

// full per-point-tile pipeline; leaves xp,yp,xpp,ypp in scope
#define COMPUTE_TILE(XV, C1, C2) \
    const float x = (XV); \
    const f32x2 x2 = {x, x}; \
    const float sa = __sinf(x), ca = __cosf(x); \
    const float cam1 = ca - 1.0f; \
    bf16x8 bv0, bv1, bt0, bt1; \
    L1STEP(C1, 0, bv0, bt0) \
    L1STEP(C1, 1, bv1, bt1) \
    const f32x4 zz = {0.0f,0.0f,0.0f,0.0f}; \
    f32x4 av0 = MFMA16(A01,bv1,MFMA16(A00,bv0,zz)); \
    f32x4 av1 = MFMA16(A11,bv1,MFMA16(A10,bv0,zz)); \
    f32x4 av2 = MFMA16(A21,bv1,MFMA16(A20,bv0,zz)); \
    f32x4 av3 = MFMA16(A31,bv1,MFMA16(A30,bv0,zz)); \
    f32x4 at0 = MFMA16(A01,bt1,MFMA16(A00,bt0,zz)); \
    f32x4 at1 = MFMA16(A11,bt1,MFMA16(A10,bt0,zz)); \
    f32x4 at2 = MFMA16(A21,bt1,MFMA16(A20,bt0,zz)); \
    f32x4 at3 = MFMA16(A31,bt1,MFMA16(A30,bt0,zz)); \
    f32x2 pv0_2 = {0.0f,0.0f}, pv1_2 = {0.0f,0.0f}; \
    f32x2 pt0_2 = {0.0f,0.0f}, pt1_2 = {0.0f,0.0f}; \
    L2STEP(C2, 0, av0, at0) \
    L2STEP(C2, 1, av1, at1) \
    L2STEP(C2, 2, av2, at2) \
    L2STEP(C2, 3, av3, at3) \
    float pv0 = pv0_2.x + pv0_2.y, pv1 = pv1_2.x + pv1_2.y; \
    float pt0 = pt0_2.x + pt0_2.y, pt1 = pt1_2.x + pt1_2.y; \
    pv0 += __shfl_xor(pv0,16); pv0 += __shfl_xor(pv0,32); \
    pv1 += __shfl_xor(pv1,16); pv1 += __shfl_xor(pv1,32); \
    pt0 += __shfl_xor(pt0,16); pt0 += __shfl_xor(pt0,32); \
    pt1 += __shfl_xor(pt1,16); pt1 += __shfl_xor(pt1,32); \
    const float z0 = pv0 + b20, z1 = pv1 + b21; \
    const float aa = z0*z0, bb = z1*z1; \
    const float da = 8.0f*z0*pt0, db = 8.0f*z1*pt1; \
    const float xp = aa*cam1, yp = bb*sa; \
    const float xpp = fmaf(da,cam1,-(aa*sa)); \
    const float ypp = fmaf(bb,ca, db*sa);

__global__ void __launch_bounds__(256, 2) sofa_kernel(
    const float* __restrict__ alpha,
    const float* __restrict__ w0,
    const float* __restrict__ w1,
    const float* __restrict__ w2,
    const float* __restrict__ b0,
    const float* __restrict__ b1,
    const float* __restrict__ b2,
    float* __restrict__ out)
{
    __shared__ __align__(16) __bf16 w1s[HDIM * HDIM];     // XOR-swizzled bf16 W1
    __shared__ float s_alpha[NHALF];
    // Dual-copy constant tables (copies identical; index by it&1 so the per-tile
    // ds_read_b128s are NOT loop-invariant -> LICM can't hoist them back into regs).
    __shared__ __align__(16) float l1tab[2][2][4][16];    // [copy][s][grp][ w0q0 w0q1 b0q0 b0q1 ] (*C2L)
    __shared__ __align__(16) float l2tab[2][4][4][12];    // [copy][q][grp][ b1c*C2L | w2a | w2b ]
    __shared__ float s_xplast;

    const int n    = blockIdx.x;
    const int tid  = threadIdx.x;
    const int lane = tid & 63;
    const int wid  = tid >> 6;
    const int col  = lane & 15;   // MFMA col (point) / A-row index
    const int grp  = lane >> 4;   // k-slot group / output-plane selector

    const float* __restrict__ w0n = w0 + (size_t)n * HDIM;
    const float* __restrict__ b0n = b0 + (size_t)n * HDIM;
    const float* __restrict__ w1n = w1 + (size_t)n * HDIM * HDIM;
    const float* __restrict__ b1n = b1 + (size_t)n * HDIM;
    const float* __restrict__ w2n = w2 + (size_t)n * 2 * HDIM;
    const float* __restrict__ b2n = b2 + (size_t)n * 2;

    // ---- stage alpha and W1 (bf16, 16B-group XOR swizzle) into LDS ----
    for (int e = tid; e < NHALF; e += 256) s_alpha[e] = alpha[e];
    for (int e4 = tid; e4 < (HDIM * HDIM) / 4; e4 += 256) {
        const int i = e4 >> 4, j4 = (e4 & 15) << 2;
        f32x4 v = ((const f32x4*)w1n)[e4];
        bf16x4 b;
        b[0] = (__bf16)v.x; b[1] = (__bf16)v.y; b[2] = (__bf16)v.z; b[3] = (__bf16)v.w;
        *(bf16x4*)&w1s[i * 64 + (((j4 >> 3) ^ (i & 7)) << 3) + (j4 & 7)] = b;
    }
    // ---- stage constant tables (both copies) ----
    for (int e = tid; e < 128; e += 256) {          // 2 s * 4 grp * 16
        const int s = e >> 6, rem = e & 63, g = rem >> 4, f = rem & 15;
        const int j = s * 32 + g * 8 + (f & 7);
        const float val = ((f < 8) ? w0n[j] : b0n[j]) * C2L;
        l1tab[0][s][g][f] = val;
        l1tab[1][s][g][f] = val;
    }
    for (int e = tid; e < 192; e += 256) {          // 4 q * 4 grp * 12
        const int q = e / 48, rem = e - q * 48, g = rem / 12, f = rem - g * 12;
        const int base = q * 16 + g * 4;
        const float val = (f < 4) ? b1n[base + f] * C2L
                        : (f < 8) ? w2n[base + f - 4]
                                  : w2n[64 + base + f - 8];
        l2tab[0][q][g][f] = val;
        l2tab[1][q][g][f] = val;
    }
    __syncthreads();

    // ---- constants for packed math ----
    const f32x2 _km2 = {-2.0f, -2.0f};
    const f32x2 _k1  = { 1.0f,  1.0f};
    const f32x2 c2l2 = { C2L,   C2L };
    const float b20 = b2n[0], b21 = b2n[1];

    // ---- A-fragments: W1 rows in registers (lane: row=col, k = 32*KH + 8*grp + 0..7) ----
    const bf16x8* w1v = (const bf16x8*)w1s;
    const int sw = col & 7;
#define AF(RT,KH) w1v[((RT)*16 + col)*8 + (((KH)*4 + grp) ^ sw)]
    const bf16x8 A00 = AF(0,0), A01 = AF(0,1), A10 = AF(1,0), A11 = AF(1,1);
    const bf16x8 A20 = AF(2,0), A21 = AF(2,1), A30 = AF(3,0), A31 = AF(3,1);

    const size_t obase = (size_t)grp * PLANE + (size_t)n * NFULL;

    // ---- point 1024 first (wave 0), to get xp_last for the xp mirror ----
    if (wid == 0) {
        const f32x4* c1 = (const f32x4*)&l1tab[0][0][grp][0];
        const f32x4* c2 = (const f32x4*)&l2tab[0][0][grp][0];
        COMPUTE_TILE(s_alpha[1024], c1, c2)
        if (col == 0) {
            out[obase + 1024] = (grp == 0) ? xp : (grp == 1) ? yp : (grp == 2) ? xpp : ypp;
            if (grp == 0) s_xplast = xp;
        }
    }
    __syncthreads();
    const float xl2 = 2.0f * s_xplast;

    // ---- main loop: 16 iters/wave, 16 points each; covers b = 0..1023 ----
    #pragma unroll 1
    for (int it = 0; it < 16; ++it) {
        const f32x4* c1 = (const f32x4*)&l1tab[it & 1][0][grp][0];
        const f32x4* c2 = (const f32x4*)&l2tab[it & 1][0][grp][0];
        const int p = ((it * 4 + wid) << 4) + col;
        COMPUTE_TILE(s_alpha[p], c1, c2)
        const float vdir = (grp == 0) ? xp : (grp == 1) ? yp : (grp == 2) ? xpp : ypp;
        const float vmir = (grp == 0) ? (xl2 - xp)
                         : (grp == 1) ? yp
                         : (grp == 2) ? xpp : -ypp;
        out[obase + p] = vdir;
        out[obase + (2048 - p)] = vmir;
    }
}

extern "C" void kernel_launch(void* const* d_in, const int* in_sizes, int n_in,
                              void* d_out, int out_size, void* d_ws, size_t ws_size,
                              hipStream_t stream) {
    const float* alpha = (const float*)d_in[0];
    const float* w0    = (const float*)d_in[1];
    const float* w1    = (const float*)d_in[2];
    const float* w2    = (const float*)d_in[3];
    const float* b0    = (const float*)d_in[4];
    const float* b1    = (const float*)d_in[5];
    const float* b2    = (const float*)d_in[6];
    float* out = (float*)d_out;
    sofa_kernel<<<dim3(N_AB), dim3(256), 0, stream>>>(alpha, w0, w1, w2, b0, b1, b2, out);
}